// Round 5
// baseline (516.925 us; speedup 1.0000x reference)
//
#include <hip/hip_runtime.h>
#include <hip/hip_fp16.h>
#include <math.h>

// AmpNorm via real-input 2D FFT, transposed fp16 half-spectrum At[img][w][h].
// w in [0,193) (Hermitian half along W), h in [0,384) contiguous (1536B rows).
// FFT-384 = 12 (register FFT) x 32 (cross-lane shuffle FFT), per 32-lane group.
// Column kernels: no LDS, direct register FFT on contiguous columns.

#define NFFT   384
#define NW     193            // half-spectrum width
#define PLANE  147456         // 384*384
#define IMGS   96
#define LSTRB  389            // K1 LDS line stride (float2)
#define TSTR   33             // K6 tile stride (half2)

__device__ __forceinline__ float2 cmul(float2 a, float2 b) {
    return make_float2(a.x*b.x - a.y*b.y, a.x*b.y + a.y*b.x);
}
__device__ __forceinline__ float2 cadd(float2 a, float2 b) { return make_float2(a.x+b.x, a.y+b.y); }
__device__ __forceinline__ float2 csub(float2 a, float2 b) { return make_float2(a.x-b.x, a.y-b.y); }

// ---- 12-point FFT in registers (12 = 3 x 4) ----
template<int DIR>
__device__ __forceinline__ void fft12(float2 z[12]) {
    const float dir = (float)DIR;
    const float H = 0.86602540378443864676f;
    float2 G[12];
    #pragma unroll
    for (int b = 0; b < 3; ++b) {
        float2 a0 = z[b], a1 = z[b+3], a2 = z[b+6], a3 = z[b+9];
        float2 t0 = cadd(a0, a2), t1 = csub(a0, a2);
        float2 t2 = cadd(a1, a3), t3 = csub(a1, a3);
        G[b*4+0] = cadd(t0, t2);
        G[b*4+1] = make_float2(t1.x + dir*t3.y, t1.y - dir*t3.x);
        G[b*4+2] = csub(t0, t2);
        G[b*4+3] = make_float2(t1.x - dir*t3.y, t1.y + dir*t3.x);
    }
    const float2 W1 = make_float2( H,    -dir*0.5f);
    const float2 W2 = make_float2( 0.5f, -dir*H);
    const float2 W3 = make_float2( 0.0f, -dir);
    const float2 W4 = make_float2(-0.5f, -dir*H);
    const float2 W6 = make_float2(-1.0f,  0.0f);
    G[4+1] = cmul(G[4+1], W1);  G[4+2] = cmul(G[4+2], W2);  G[4+3] = cmul(G[4+3], W3);
    G[8+1] = cmul(G[8+1], W2);  G[8+2] = cmul(G[8+2], W4);  G[8+3] = cmul(G[8+3], W6);
    const float b3 = -dir * H;
    #pragma unroll
    for (int ka = 0; ka < 4; ++ka) {
        float2 g0 = G[ka], g1 = G[4+ka], g2 = G[8+ka];
        float2 t = cadd(g1, g2), d = csub(g1, g2);
        float2 u = make_float2(g0.x - 0.5f*t.x, g0.y - 0.5f*t.y);
        z[ka]   = cadd(g0, t);
        z[ka+4] = make_float2(u.x - b3*d.y, u.y + b3*d.x);
        z[ka+8] = make_float2(u.x + b3*d.y, u.y - b3*d.x);
    }
}

struct Tw32 { float2 w16, w8, w4, w2; float s16, s8, s4, s2, s1; };

template<int DIR>
__device__ __forceinline__ float2 stage_w(int l, int m) {
    if (l & m) {
        float ph = 3.14159265358979323846f * (float)(l & (m-1)) / (float)m;
        float sv, cv; sincosf(ph, &sv, &cv);
        return make_float2(cv, -(float)DIR * sv);
    }
    return make_float2(1.0f, 0.0f);
}

template<int DIR>
__device__ __forceinline__ Tw32 make_tw32(int l) {
    Tw32 T;
    T.w16 = stage_w<DIR>(l, 16);
    T.w8  = stage_w<DIR>(l, 8);
    T.w4  = stage_w<DIR>(l, 4);
    T.w2  = (l & 2) ? ((l & 1) ? make_float2(0.0f, -(float)DIR) : make_float2(1.0f, 0.0f))
                    : make_float2(1.0f, 0.0f);
    T.s16 = (l & 16) ? -1.0f : 1.0f;
    T.s8  = (l & 8)  ? -1.0f : 1.0f;
    T.s4  = (l & 4)  ? -1.0f : 1.0f;
    T.s2  = (l & 2)  ? -1.0f : 1.0f;
    T.s1  = (l & 1)  ? -1.0f : 1.0f;
    return T;
}

__device__ __forceinline__ float2 bfly(float2 v, int mask, float s, float2 w) {
    float2 p, t;
    p.x = __shfl_xor(v.x, mask, 64);
    p.y = __shfl_xor(v.y, mask, 64);
    t.x = fmaf(s, v.x, p.x);
    t.y = fmaf(s, v.y, p.y);
    return cmul(t, w);
}

__device__ __forceinline__ float2 fft32_slot(float2 v, const Tw32& T) {
    v = bfly(v, 16, T.s16, T.w16);
    v = bfly(v, 8,  T.s8,  T.w8);
    v = bfly(v, 4,  T.s4,  T.w4);
    v = bfly(v, 2,  T.s2,  T.w2);
    float2 p;
    p.x = __shfl_xor(v.x, 1, 64);
    p.y = __shfl_xor(v.y, 1, 64);
    v.x = fmaf(T.s1, v.x, p.x);
    v.y = fmaf(T.s1, v.y, p.y);
    return v;
}

// input z[j] = x[32j + l]; output z[k] = X[k + 12*bitrev5(l)]
template<int DIR>
__device__ __forceinline__ void fft384_reg(float2 z[12], int l) {
    fft12<DIR>(z);
    float ang = (6.28318530717958647692f / 384.0f) * (float)l;
    float sv, cv; sincosf(ang, &sv, &cv);
    float2 w1 = make_float2(cv, -(float)DIR * sv);
    float2 wk = w1;
    z[1] = cmul(z[1], wk);
    #pragma unroll
    for (int k = 2; k < 12; ++k) { wk = cmul(wk, w1); z[k] = cmul(z[k], wk); }
    Tw32 T = make_tw32<DIR>(l);
    #pragma unroll
    for (int k = 0; k < 12; ++k) z[k] = fft32_slot(z[k], T);
}

// ---- K1: forward row FFT (2 real rows packed), write transposed At[w][h] ----
__global__ __launch_bounds__(256, 3) void k_fft_rows_fwd(const float* __restrict__ x,
                                                         __half2* __restrict__ At) {
    __shared__ float2 lbuf[16 * LSTRB];
    int tid = threadIdx.x, grp = tid >> 5, l = tid & 31;
    int img = blockIdx.x / 12, g = blockIdx.x % 12;     // g: 32-row group
    const float* xi = x + (size_t)img * PLANE + (size_t)g * 32 * NFFT;
    #pragma unroll
    for (int pp = 0; pp < 2; ++pp) {
        int p = grp + 8 * pp;                           // local row-pair [0,16)
        const float* xa = xi + (size_t)(2 * p) * NFFT;
        const float* xb = xa + NFFT;
        float2 z[12];
        #pragma unroll
        for (int j = 0; j < 12; ++j) z[j] = make_float2(xa[32*j + l], xb[32*j + l]);
        fft384_reg<1>(z, l);
        int r = __brev((unsigned)l) >> 27;
        float2* s = lbuf + p * LSTRB;
        #pragma unroll
        for (int k = 0; k < 12; ++k) s[k + 12*r] = z[k];
    }
    __syncthreads();
    int h0 = g * 32;
    int q = l >> 1, odd = l & 1;
    #pragma unroll
    for (int pass = 0; pass < 13; ++pass) {
        #pragma unroll
        for (int ww = 0; ww < 2; ++ww) {
            int w = pass * 16 + grp * 2 + ww;
            if (w <= 192) {
                float2 Z  = lbuf[q * LSTRB + w];
                float2 Zm = lbuf[q * LSTRB + (w == 0 ? 0 : NFFT - w)];
                float2 v;
                if (odd) v = make_float2( 0.5f * (Z.y + Zm.y), -0.5f * (Z.x - Zm.x));  // Fb
                else     v = make_float2( 0.5f * (Z.x + Zm.x),  0.5f * (Z.y - Zm.y));  // Fa
                At[((size_t)img * NW + w) * NFFT + h0 + l] = __floats2half2_rn(v.x, v.y);
            }
        }
    }
}

// ---- K2: forward column FFT on contiguous columns + atomic amp accumulation ----
__global__ __launch_bounds__(256, 6) void k_fft_cols_fwd(__half2* __restrict__ At,
                                                         float* __restrict__ ampm) {
    int tid = threadIdx.x, grp = tid >> 5, l = tid & 31;
    int img = blockIdx.x / 13, cg = blockIdx.x % 13;
    int c = img % 3;
    #pragma unroll
    for (int cc = 0; cc < 2; ++cc) {
        int w = cg * 16 + grp * 2 + cc;
        if (w > 192) continue;
        __half2* col = At + ((size_t)img * NW + w) * NFFT;
        float*   ac  = ampm + ((size_t)c * NW + w) * NFFT;
        float2 z[12];
        #pragma unroll
        for (int j = 0; j < 12; ++j) z[j] = __half22float2(col[32*j + l]);
        fft384_reg<1>(z, l);
        int r = __brev((unsigned)l) >> 27;
        #pragma unroll
        for (int k = 0; k < 12; ++k) {
            int n = k + 12*r;
            col[n] = __floats2half2_rn(z[k].x, z[k].y);
            atomicAdd(ac + n, sqrtf(z[k].x*z[k].x + z[k].y*z[k].y));
        }
    }
}

// ---- K3: flag = sum(running_amp) via block partial + atomic ----
__global__ __launch_bounds__(256) void k_flag(const float* __restrict__ r,
                                              float* __restrict__ flag) {
    __shared__ float sm[256];
    int t = blockIdx.x * 1024 + threadIdx.x * 4;
    float4 v = *(const float4*)(r + t);
    sm[threadIdx.x] = v.x + v.y + v.z + v.w;
    __syncthreads();
    for (int s = 128; s > 0; s >>= 1) {
        if (threadIdx.x < s) sm[threadIdx.x] += sm[threadIdx.x + s];
        __syncthreads();
    }
    if (threadIdx.x == 0) atomicAdd(flag, sm[0]);
}

// ---- K5: rescale + inverse column FFT (contiguous columns, no LDS) ----
__global__ __launch_bounds__(256, 6) void k_ifft_cols_scale(__half2* __restrict__ At,
                                                            const float* __restrict__ ampm,
                                                            const float* __restrict__ running,
                                                            const float* __restrict__ flag) {
    int tid = threadIdx.x, grp = tid >> 5, l = tid & 31;
    int img = blockIdx.x / 13, cg = blockIdx.x % 13;
    int c = img % 3;
    bool adopt = (flag[0] == 0.0f);
    const float inv = 1.0f / (float)NFFT;
    #pragma unroll
    for (int cc = 0; cc < 2; ++cc) {
        int w = cg * 16 + grp * 2 + cc;
        if (w > 192) continue;
        __half2*     col = At + ((size_t)img * NW + w) * NFFT;
        const float* ac  = ampm + ((size_t)c * NW + w) * NFFT;
        float2 z[12];
        #pragma unroll
        for (int j = 0; j < 12; ++j) {
            int n = 32*j + l;
            float2 zv = __half22float2(col[n]);
            float am = ac[n] * (1.0f / 32.0f);
            float na;
            if (adopt) na = am;
            else na = 0.9f * running[((size_t)c * NFFT + n) * NFFT + w] + 0.1f * am;
            float mag = sqrtf(zv.x*zv.x + zv.y*zv.y);
            if (mag > 0.0f) { float sc = na / mag; z[j] = make_float2(zv.x*sc, zv.y*sc); }
            else            { z[j] = make_float2(na, 0.0f); }
        }
        fft384_reg<-1>(z, l);
        int r = __brev((unsigned)l) >> 27;
        #pragma unroll
        for (int k = 0; k < 12; ++k)
            col[k + 12*r] = __floats2half2_rn(z[k].x * inv, z[k].y * inv);
    }
}

// ---- K6: inverse row FFT (C2R) via LDS tile of At[w][h0..h0+31] ----
__global__ __launch_bounds__(256, 5) void k_ifft_rows_out(const __half2* __restrict__ At,
                                                          float* __restrict__ out) {
    __shared__ __half2 tile[NW * TSTR];
    int tid = threadIdx.x, grp = tid >> 5, l = tid & 31;
    int img = blockIdx.x / 12, g = blockIdx.x % 12;
    int h0 = g * 32;
    #pragma unroll
    for (int i = 0; i < 25; ++i) {
        int idx = i * 256 + tid;
        if (idx < NW * 32) {
            int w = idx >> 5, hh = idx & 31;
            tile[w * TSTR + hh] = At[((size_t)img * NW + w) * NFFT + h0 + hh];
        }
    }
    __syncthreads();
    const float inv = 1.0f / (float)NFFT;
    #pragma unroll
    for (int pp = 0; pp < 2; ++pp) {
        int q = grp + 8 * pp;                       // local row-pair [0,16)
        float2 z[12];
        #pragma unroll
        for (int j = 0; j < 12; ++j) {
            int n = 32*j + l;
            if (n <= 192) {
                float2 Fa = __half22float2(tile[n * TSTR + 2*q]);
                float2 Fb = __half22float2(tile[n * TSTR + 2*q + 1]);
                z[j] = make_float2(Fa.x - Fb.y, Fa.y + Fb.x);
            } else {
                int m2 = NFFT - n;
                float2 Fa = __half22float2(tile[m2 * TSTR + 2*q]);
                float2 Fb = __half22float2(tile[m2 * TSTR + 2*q + 1]);
                z[j] = make_float2(Fa.x + Fb.y, Fb.x - Fa.y);
            }
        }
        fft384_reg<-1>(z, l);
        int r = __brev((unsigned)l) >> 27;
        float* oa = out + (size_t)img * PLANE + (size_t)(h0 + 2*q) * NFFT;
        float* ob = oa + NFFT;
        #pragma unroll
        for (int k = 0; k < 12; ++k) {
            int n = k + 12*r;
            oa[n] = z[k].x * inv;
            ob[n] = z[k].y * inv;
        }
    }
}

extern "C" void kernel_launch(void* const* d_in, const int* in_sizes, int n_in,
                              void* d_out, int out_size, void* d_ws, size_t ws_size,
                              hipStream_t stream) {
    const float* x       = (const float*)d_in[0];
    const float* running = (const float*)d_in[1];
    float* out = (float*)d_out;

    char* ws = (char*)d_ws;
    __half2* At   = (__half2*)ws;                       // 96*193*384*4 = 28,459,008 B
    float*   ampm = (float*)(ws + 28459008);            // 3*193*384*4 =     889,344 B
    float*   flag = (float*)(ws + 28459008 + 889344);   // 4 B

    hipMemsetAsync(ampm, 0, 889344 + 4, stream);        // zero ampm + flag
    k_flag<<<432, 256, 0, stream>>>(running, flag);
    k_fft_rows_fwd<<<IMGS * 12, 256, 0, stream>>>(x, At);
    k_fft_cols_fwd<<<IMGS * 13, 256, 0, stream>>>(At, ampm);
    k_ifft_cols_scale<<<IMGS * 13, 256, 0, stream>>>(At, ampm, running, flag);
    k_ifft_rows_out<<<IMGS * 12, 256, 0, stream>>>(At, out);
}

// Round 6
// 226.693 us; speedup vs baseline: 2.2803x; 2.2803x over previous
//
#include <hip/hip_runtime.h>
#include <hip/hip_fp16.h>
#include <math.h>

// AmpNorm via real-input 2D FFT, transposed fp16 half-spectrum At[img][w][h].
// w in [0,193) (Hermitian half along W), h in [0,384) contiguous (1536B rows).
// FFT-384 = 12 (register FFT) x 32 (cross-lane shuffle FFT), per 32-lane group.
// Column kernels: no LDS, no atomics; one w per 32-lane group, grid 96*25.

#define NFFT   384
#define NW     193            // half-spectrum width
#define PLANE  147456         // 384*384
#define IMGS   96
#define LSTRB  389            // K1 LDS line stride (float2)
#define TSTR   33             // K6 tile stride (half2)

__device__ __forceinline__ float2 cmul(float2 a, float2 b) {
    return make_float2(a.x*b.x - a.y*b.y, a.x*b.y + a.y*b.x);
}
__device__ __forceinline__ float2 cadd(float2 a, float2 b) { return make_float2(a.x+b.x, a.y+b.y); }
__device__ __forceinline__ float2 csub(float2 a, float2 b) { return make_float2(a.x-b.x, a.y-b.y); }

// ---- 12-point FFT in registers (12 = 3 x 4) ----
template<int DIR>
__device__ __forceinline__ void fft12(float2 z[12]) {
    const float dir = (float)DIR;
    const float H = 0.86602540378443864676f;
    float2 G[12];
    #pragma unroll
    for (int b = 0; b < 3; ++b) {
        float2 a0 = z[b], a1 = z[b+3], a2 = z[b+6], a3 = z[b+9];
        float2 t0 = cadd(a0, a2), t1 = csub(a0, a2);
        float2 t2 = cadd(a1, a3), t3 = csub(a1, a3);
        G[b*4+0] = cadd(t0, t2);
        G[b*4+1] = make_float2(t1.x + dir*t3.y, t1.y - dir*t3.x);
        G[b*4+2] = csub(t0, t2);
        G[b*4+3] = make_float2(t1.x - dir*t3.y, t1.y + dir*t3.x);
    }
    const float2 W1 = make_float2( H,    -dir*0.5f);
    const float2 W2 = make_float2( 0.5f, -dir*H);
    const float2 W3 = make_float2( 0.0f, -dir);
    const float2 W4 = make_float2(-0.5f, -dir*H);
    const float2 W6 = make_float2(-1.0f,  0.0f);
    G[4+1] = cmul(G[4+1], W1);  G[4+2] = cmul(G[4+2], W2);  G[4+3] = cmul(G[4+3], W3);
    G[8+1] = cmul(G[8+1], W2);  G[8+2] = cmul(G[8+2], W4);  G[8+3] = cmul(G[8+3], W6);
    const float b3 = -dir * H;
    #pragma unroll
    for (int ka = 0; ka < 4; ++ka) {
        float2 g0 = G[ka], g1 = G[4+ka], g2 = G[8+ka];
        float2 t = cadd(g1, g2), d = csub(g1, g2);
        float2 u = make_float2(g0.x - 0.5f*t.x, g0.y - 0.5f*t.y);
        z[ka]   = cadd(g0, t);
        z[ka+4] = make_float2(u.x - b3*d.y, u.y + b3*d.x);
        z[ka+8] = make_float2(u.x + b3*d.y, u.y - b3*d.x);
    }
}

struct Tw32 { float2 w16, w8, w4, w2; float s16, s8, s4, s2, s1; };

template<int DIR>
__device__ __forceinline__ float2 stage_w(int l, int m) {
    if (l & m) {
        float ph = 3.14159265358979323846f * (float)(l & (m-1)) / (float)m;
        float sv, cv; sincosf(ph, &sv, &cv);
        return make_float2(cv, -(float)DIR * sv);
    }
    return make_float2(1.0f, 0.0f);
}

template<int DIR>
__device__ __forceinline__ Tw32 make_tw32(int l) {
    Tw32 T;
    T.w16 = stage_w<DIR>(l, 16);
    T.w8  = stage_w<DIR>(l, 8);
    T.w4  = stage_w<DIR>(l, 4);
    T.w2  = (l & 2) ? ((l & 1) ? make_float2(0.0f, -(float)DIR) : make_float2(1.0f, 0.0f))
                    : make_float2(1.0f, 0.0f);
    T.s16 = (l & 16) ? -1.0f : 1.0f;
    T.s8  = (l & 8)  ? -1.0f : 1.0f;
    T.s4  = (l & 4)  ? -1.0f : 1.0f;
    T.s2  = (l & 2)  ? -1.0f : 1.0f;
    T.s1  = (l & 1)  ? -1.0f : 1.0f;
    return T;
}

__device__ __forceinline__ float2 bfly(float2 v, int mask, float s, float2 w) {
    float2 p, t;
    p.x = __shfl_xor(v.x, mask, 64);
    p.y = __shfl_xor(v.y, mask, 64);
    t.x = fmaf(s, v.x, p.x);
    t.y = fmaf(s, v.y, p.y);
    return cmul(t, w);
}

__device__ __forceinline__ float2 fft32_slot(float2 v, const Tw32& T) {
    v = bfly(v, 16, T.s16, T.w16);
    v = bfly(v, 8,  T.s8,  T.w8);
    v = bfly(v, 4,  T.s4,  T.w4);
    v = bfly(v, 2,  T.s2,  T.w2);
    float2 p;
    p.x = __shfl_xor(v.x, 1, 64);
    p.y = __shfl_xor(v.y, 1, 64);
    v.x = fmaf(T.s1, v.x, p.x);
    v.y = fmaf(T.s1, v.y, p.y);
    return v;
}

// input z[j] = x[32j + l]; output z[k] = X[k + 12*bitrev5(l)]
template<int DIR>
__device__ __forceinline__ void fft384_reg(float2 z[12], int l) {
    fft12<DIR>(z);
    float ang = (6.28318530717958647692f / 384.0f) * (float)l;
    float sv, cv; sincosf(ang, &sv, &cv);
    float2 w1 = make_float2(cv, -(float)DIR * sv);
    float2 wk = w1;
    z[1] = cmul(z[1], wk);
    #pragma unroll
    for (int k = 2; k < 12; ++k) { wk = cmul(wk, w1); z[k] = cmul(z[k], wk); }
    Tw32 T = make_tw32<DIR>(l);
    #pragma unroll
    for (int k = 0; k < 12; ++k) z[k] = fft32_slot(z[k], T);
}

// ---- K1: forward row FFT (2 real rows packed), write transposed At[w][h] ----
__global__ __launch_bounds__(256, 3) void k_fft_rows_fwd(const float* __restrict__ x,
                                                         __half2* __restrict__ At) {
    __shared__ float2 lbuf[16 * LSTRB];
    int tid = threadIdx.x, grp = tid >> 5, l = tid & 31;
    int img = blockIdx.x / 12, g = blockIdx.x % 12;     // g: 32-row group
    const float* xi = x + (size_t)img * PLANE + (size_t)g * 32 * NFFT;
    #pragma unroll
    for (int pp = 0; pp < 2; ++pp) {
        int p = grp + 8 * pp;                           // local row-pair [0,16)
        const float* xa = xi + (size_t)(2 * p) * NFFT;
        const float* xb = xa + NFFT;
        float2 z[12];
        #pragma unroll
        for (int j = 0; j < 12; ++j) z[j] = make_float2(xa[32*j + l], xb[32*j + l]);
        fft384_reg<1>(z, l);
        int r = __brev((unsigned)l) >> 27;
        float2* s = lbuf + p * LSTRB;
        #pragma unroll
        for (int k = 0; k < 12; ++k) s[k + 12*r] = z[k];
    }
    __syncthreads();
    int h0 = g * 32;
    int q = l >> 1, odd = l & 1;
    #pragma unroll
    for (int pass = 0; pass < 13; ++pass) {
        #pragma unroll
        for (int ww = 0; ww < 2; ++ww) {
            int w = pass * 16 + grp * 2 + ww;
            if (w <= 192) {
                float2 Z  = lbuf[q * LSTRB + w];
                float2 Zm = lbuf[q * LSTRB + (w == 0 ? 0 : NFFT - w)];
                float2 v;
                if (odd) v = make_float2( 0.5f * (Z.y + Zm.y), -0.5f * (Z.x - Zm.x));  // Fb
                else     v = make_float2( 0.5f * (Z.x + Zm.x),  0.5f * (Z.y - Zm.y));  // Fa
                At[((size_t)img * NW + w) * NFFT + h0 + l] = __floats2half2_rn(v.x, v.y);
            }
        }
    }
}

// ---- K2: forward column FFT on contiguous columns (no LDS, no atomics) ----
__global__ __launch_bounds__(256, 8) void k_fft_cols_fwd(__half2* __restrict__ At) {
    int tid = threadIdx.x, grp = tid >> 5, l = tid & 31;
    int img = blockIdx.x / 25, cg = blockIdx.x % 25;
    int w = cg * 8 + grp;
    if (w > 192) return;                     // uniform per 32-lane group
    __half2* col = At + ((size_t)img * NW + w) * NFFT;
    float2 z[12];
    #pragma unroll
    for (int j = 0; j < 12; ++j) z[j] = __half22float2(col[32*j + l]);
    fft384_reg<1>(z, l);
    int r = __brev((unsigned)l) >> 27;
    #pragma unroll
    for (int k = 0; k < 12; ++k)
        col[k + 12*r] = __floats2half2_rn(z[k].x, z[k].y);
}

// ---- K3: flag = sum(running_amp) via block partial + atomic ----
__global__ __launch_bounds__(256) void k_flag(const float* __restrict__ r,
                                              float* __restrict__ flag) {
    __shared__ float sm[256];
    int t = blockIdx.x * 1024 + threadIdx.x * 4;
    float4 v = *(const float4*)(r + t);
    sm[threadIdx.x] = v.x + v.y + v.z + v.w;
    __syncthreads();
    for (int s = 128; s > 0; s >>= 1) {
        if (threadIdx.x < s) sm[threadIdx.x] += sm[threadIdx.x + s];
        __syncthreads();
    }
    if (threadIdx.x == 0) atomicAdd(flag, sm[0]);
}

// ---- K4: batch-mean amplitude; block = (c,w), threads over h ----
__global__ __launch_bounds__(384) void k_amp(const __half2* __restrict__ At,
                                             float* __restrict__ ampm) {
    int c = blockIdx.x / NW;
    int w = blockIdx.x - c * NW;
    int h = threadIdx.x;
    const __half2* base = At + (size_t)w * NFFT + h;
    float s = 0.0f;
    #pragma unroll 4
    for (int b = 0; b < 32; ++b) {
        float2 z = __half22float2(base[(size_t)(b * 3 + c) * (NW * NFFT)]);
        s += sqrtf(z.x * z.x + z.y * z.y);
    }
    ampm[((size_t)c * NW + w) * NFFT + h] = s * (1.0f / 32.0f);
}

// ---- K5: rescale + inverse column FFT (contiguous columns, no LDS) ----
__global__ __launch_bounds__(256, 8) void k_ifft_cols_scale(__half2* __restrict__ At,
                                                            const float* __restrict__ ampm,
                                                            const float* __restrict__ running,
                                                            const float* __restrict__ flag) {
    int tid = threadIdx.x, grp = tid >> 5, l = tid & 31;
    int img = blockIdx.x / 25, cg = blockIdx.x % 25;
    int w = cg * 8 + grp;
    if (w > 192) return;
    int c = img % 3;
    bool adopt = (flag[0] == 0.0f);
    const float inv = 1.0f / (float)NFFT;
    __half2*     col = At + ((size_t)img * NW + w) * NFFT;
    const float* ac  = ampm + ((size_t)c * NW + w) * NFFT;
    float2 z[12];
    #pragma unroll
    for (int j = 0; j < 12; ++j) {
        int n = 32*j + l;
        float2 zv = __half22float2(col[n]);
        float am = ac[n];
        float na;
        if (adopt) na = am;
        else na = 0.9f * running[((size_t)c * NFFT + n) * NFFT + w] + 0.1f * am;
        float mag = sqrtf(zv.x*zv.x + zv.y*zv.y);
        if (mag > 0.0f) { float sc = na / mag; z[j] = make_float2(zv.x*sc, zv.y*sc); }
        else            { z[j] = make_float2(na, 0.0f); }
    }
    fft384_reg<-1>(z, l);
    int r = __brev((unsigned)l) >> 27;
    #pragma unroll
    for (int k = 0; k < 12; ++k)
        col[k + 12*r] = __floats2half2_rn(z[k].x * inv, z[k].y * inv);
}

// ---- K6: inverse row FFT (C2R) via LDS tile of At[w][h0..h0+31] ----
__global__ __launch_bounds__(256, 5) void k_ifft_rows_out(const __half2* __restrict__ At,
                                                          float* __restrict__ out) {
    __shared__ __half2 tile[NW * TSTR];
    int tid = threadIdx.x, grp = tid >> 5, l = tid & 31;
    int img = blockIdx.x / 12, g = blockIdx.x % 12;
    int h0 = g * 32;
    #pragma unroll
    for (int i = 0; i < 25; ++i) {
        int idx = i * 256 + tid;
        if (idx < NW * 32) {
            int w = idx >> 5, hh = idx & 31;
            tile[w * TSTR + hh] = At[((size_t)img * NW + w) * NFFT + h0 + hh];
        }
    }
    __syncthreads();
    const float inv = 1.0f / (float)NFFT;
    #pragma unroll
    for (int pp = 0; pp < 2; ++pp) {
        int q = grp + 8 * pp;                       // local row-pair [0,16)
        float2 z[12];
        #pragma unroll
        for (int j = 0; j < 12; ++j) {
            int n = 32*j + l;
            if (n <= 192) {
                float2 Fa = __half22float2(tile[n * TSTR + 2*q]);
                float2 Fb = __half22float2(tile[n * TSTR + 2*q + 1]);
                z[j] = make_float2(Fa.x - Fb.y, Fa.y + Fb.x);
            } else {
                int m2 = NFFT - n;
                float2 Fa = __half22float2(tile[m2 * TSTR + 2*q]);
                float2 Fb = __half22float2(tile[m2 * TSTR + 2*q + 1]);
                z[j] = make_float2(Fa.x + Fb.y, Fb.x - Fa.y);
            }
        }
        fft384_reg<-1>(z, l);
        int r = __brev((unsigned)l) >> 27;
        float* oa = out + (size_t)img * PLANE + (size_t)(h0 + 2*q) * NFFT;
        float* ob = oa + NFFT;
        #pragma unroll
        for (int k = 0; k < 12; ++k) {
            int n = k + 12*r;
            oa[n] = z[k].x * inv;
            ob[n] = z[k].y * inv;
        }
    }
}

extern "C" void kernel_launch(void* const* d_in, const int* in_sizes, int n_in,
                              void* d_out, int out_size, void* d_ws, size_t ws_size,
                              hipStream_t stream) {
    const float* x       = (const float*)d_in[0];
    const float* running = (const float*)d_in[1];
    float* out = (float*)d_out;

    char* ws = (char*)d_ws;
    __half2* At   = (__half2*)ws;                       // 96*193*384*4 = 28,459,008 B
    float*   ampm = (float*)(ws + 28459008);            // 3*193*384*4 =     889,344 B
    float*   flag = (float*)(ws + 28459008 + 889344);   // 4 B

    hipMemsetAsync(flag, 0, 4, stream);
    k_flag<<<432, 256, 0, stream>>>(running, flag);
    k_fft_rows_fwd<<<IMGS * 12, 256, 0, stream>>>(x, At);
    k_fft_cols_fwd<<<IMGS * 25, 256, 0, stream>>>(At);
    k_amp<<<3 * NW, 384, 0, stream>>>(At, ampm);
    k_ifft_cols_scale<<<IMGS * 25, 256, 0, stream>>>(At, ampm, running, flag);
    k_ifft_rows_out<<<IMGS * 12, 256, 0, stream>>>(At, out);
}

// Round 7
// 211.965 us; speedup vs baseline: 2.4387x; 1.0695x over previous
//
#include <hip/hip_runtime.h>
#include <hip/hip_fp16.h>
#include <math.h>

// AmpNorm via real-input 2D FFT, transposed fp16 half-spectrum At[img][w][h].
// Forward col FFT stores P-layout (P[k*32+l] = X[k+12*bitrev5(l)]) contiguously;
// inverse col FFT consumes P-layout via DIT shuffle FFT and stores natural order.
// All global loads/stores in the col kernels and K6 output are 128B-coalesced.

#define NFFT   384
#define NW     193            // half-spectrum width
#define PLANE  147456         // 384*384
#define IMGS   96
#define LSTRB  389            // K1 LDS line stride (float2)
#define TSTR   33             // K6 tile stride (half2)

__device__ __forceinline__ float2 cmul(float2 a, float2 b) {
    return make_float2(a.x*b.x - a.y*b.y, a.x*b.y + a.y*b.x);
}
__device__ __forceinline__ float2 cadd(float2 a, float2 b) { return make_float2(a.x+b.x, a.y+b.y); }
__device__ __forceinline__ float2 csub(float2 a, float2 b) { return make_float2(a.x-b.x, a.y-b.y); }

// ---- 12-point DFT in registers (12 = 3 x 4), kernel e^{-DIR*2pi*i*t*f/12} ----
template<int DIR>
__device__ __forceinline__ void fft12(float2 z[12]) {
    const float dir = (float)DIR;
    const float H = 0.86602540378443864676f;
    float2 G[12];
    #pragma unroll
    for (int b = 0; b < 3; ++b) {
        float2 a0 = z[b], a1 = z[b+3], a2 = z[b+6], a3 = z[b+9];
        float2 t0 = cadd(a0, a2), t1 = csub(a0, a2);
        float2 t2 = cadd(a1, a3), t3 = csub(a1, a3);
        G[b*4+0] = cadd(t0, t2);
        G[b*4+1] = make_float2(t1.x + dir*t3.y, t1.y - dir*t3.x);
        G[b*4+2] = csub(t0, t2);
        G[b*4+3] = make_float2(t1.x - dir*t3.y, t1.y + dir*t3.x);
    }
    const float2 W1 = make_float2( H,    -dir*0.5f);
    const float2 W2 = make_float2( 0.5f, -dir*H);
    const float2 W3 = make_float2( 0.0f, -dir);
    const float2 W4 = make_float2(-0.5f, -dir*H);
    const float2 W6 = make_float2(-1.0f,  0.0f);
    G[4+1] = cmul(G[4+1], W1);  G[4+2] = cmul(G[4+2], W2);  G[4+3] = cmul(G[4+3], W3);
    G[8+1] = cmul(G[8+1], W2);  G[8+2] = cmul(G[8+2], W4);  G[8+3] = cmul(G[8+3], W6);
    const float b3 = -dir * H;
    #pragma unroll
    for (int ka = 0; ka < 4; ++ka) {
        float2 g0 = G[ka], g1 = G[4+ka], g2 = G[8+ka];
        float2 t = cadd(g1, g2), d = csub(g1, g2);
        float2 u = make_float2(g0.x - 0.5f*t.x, g0.y - 0.5f*t.y);
        z[ka]   = cadd(g0, t);
        z[ka+4] = make_float2(u.x - b3*d.y, u.y + b3*d.x);
        z[ka+8] = make_float2(u.x + b3*d.y, u.y - b3*d.x);
    }
}

// ======== DIF cross-lane 32-FFT (forward): natural in, bit-reversed out ========
struct Tw32 { float2 w16, w8, w4, w2; float s16, s8, s4, s2, s1; };

template<int DIR>
__device__ __forceinline__ float2 stage_w(int l, int m) {
    if (l & m) {
        float ph = 3.14159265358979323846f * (float)(l & (m-1)) / (float)m;
        float sv, cv; sincosf(ph, &sv, &cv);
        return make_float2(cv, -(float)DIR * sv);
    }
    return make_float2(1.0f, 0.0f);
}

template<int DIR>
__device__ __forceinline__ Tw32 make_tw32(int l) {
    Tw32 T;
    T.w16 = stage_w<DIR>(l, 16);
    T.w8  = stage_w<DIR>(l, 8);
    T.w4  = stage_w<DIR>(l, 4);
    T.w2  = (l & 2) ? ((l & 1) ? make_float2(0.0f, -(float)DIR) : make_float2(1.0f, 0.0f))
                    : make_float2(1.0f, 0.0f);
    T.s16 = (l & 16) ? -1.0f : 1.0f;
    T.s8  = (l & 8)  ? -1.0f : 1.0f;
    T.s4  = (l & 4)  ? -1.0f : 1.0f;
    T.s2  = (l & 2)  ? -1.0f : 1.0f;
    T.s1  = (l & 1)  ? -1.0f : 1.0f;
    return T;
}

__device__ __forceinline__ float2 bfly(float2 v, int mask, float s, float2 w) {
    float2 p, t;
    p.x = __shfl_xor(v.x, mask, 64);
    p.y = __shfl_xor(v.y, mask, 64);
    t.x = fmaf(s, v.x, p.x);
    t.y = fmaf(s, v.y, p.y);
    return cmul(t, w);
}

__device__ __forceinline__ float2 fft32_slot(float2 v, const Tw32& T) {
    v = bfly(v, 16, T.s16, T.w16);
    v = bfly(v, 8,  T.s8,  T.w8);
    v = bfly(v, 4,  T.s4,  T.w4);
    v = bfly(v, 2,  T.s2,  T.w2);
    float2 p;
    p.x = __shfl_xor(v.x, 1, 64);
    p.y = __shfl_xor(v.y, 1, 64);
    v.x = fmaf(T.s1, v.x, p.x);
    v.y = fmaf(T.s1, v.y, p.y);
    return v;
}

// forward: input z[j] = x[32j + l]; output z[k] = X[k + 12*bitrev5(l)]
template<int DIR>
__device__ __forceinline__ void fft384_reg(float2 z[12], int l) {
    fft12<DIR>(z);
    float ang = (6.28318530717958647692f / 384.0f) * (float)l;
    float sv, cv; sincosf(ang, &sv, &cv);
    float2 w1 = make_float2(cv, -(float)DIR * sv);
    float2 wk = w1;
    z[1] = cmul(z[1], wk);
    #pragma unroll
    for (int k = 2; k < 12; ++k) { wk = cmul(wk, w1); z[k] = cmul(z[k], wk); }
    Tw32 T = make_tw32<DIR>(l);
    #pragma unroll
    for (int k = 0; k < 12; ++k) z[k] = fft32_slot(z[k], T);
}

// ======== DIT cross-lane 32-FFT (inverse): bit-reversed in, natural out ========
struct TwD { float2 w2, w4, w8, w16; };

template<int DIR>
__device__ __forceinline__ float2 dit_stage_w(int l, int mask) {
    float ph = 3.14159265358979323846f * (float)(l & (mask-1)) / (float)mask;
    float sv, cv; sincosf(ph, &sv, &cv);
    return make_float2(cv, -(float)DIR * sv);   // e^{-DIR*2pi*i*r/(2*mask)}
}

template<int DIR>
__device__ __forceinline__ TwD make_twd(int l) {
    TwD T;
    T.w2  = (l & 1) ? make_float2(0.0f, -(float)DIR) : make_float2(1.0f, 0.0f);
    T.w4  = dit_stage_w<DIR>(l, 4);
    T.w8  = dit_stage_w<DIR>(l, 8);
    T.w16 = dit_stage_w<DIR>(l, 16);
    return T;
}

__device__ __forceinline__ float2 dit_bfly(float2 v, int mask, int hi, float2 w) {
    float2 b = hi ? cmul(w, v) : v;
    float2 p;
    p.x = __shfl_xor(b.x, mask, 64);
    p.y = __shfl_xor(b.y, mask, 64);
    float s = hi ? -1.0f : 1.0f;
    return make_float2(fmaf(s, b.x, p.x), fmaf(s, b.y, p.y));
}

__device__ __forceinline__ float2 dit32_slot(float2 v, const TwD& T, int l) {
    {   // mask=1, W=1
        float2 p;
        p.x = __shfl_xor(v.x, 1, 64);
        p.y = __shfl_xor(v.y, 1, 64);
        float s = (l & 1) ? -1.0f : 1.0f;
        v = make_float2(fmaf(s, v.x, p.x), fmaf(s, v.y, p.y));
    }
    v = dit_bfly(v, 2,  l & 2,  T.w2);
    v = dit_bfly(v, 4,  l & 4,  T.w4);
    v = dit_bfly(v, 8,  l & 8,  T.w8);
    v = dit_bfly(v, 16, l & 16, T.w16);
    return v;
}

// inverse: input zk[k] = X[k + 12*bitrev5(l)]; output zk[j] = Y[32j + l]
__device__ __forceinline__ void ifft384_dit(float2 zk[12], int l) {
    TwD T = make_twd<-1>(l);
    #pragma unroll
    for (int k = 0; k < 12; ++k) zk[k] = dit32_slot(zk[k], T, l);
    float ang = (6.28318530717958647692f / 384.0f) * (float)l;
    float sv, cv; sincosf(ang, &sv, &cv);
    float2 w1 = make_float2(cv, sv);             // e^{+2pi*i*l/384}
    float2 wk = w1;
    zk[1] = cmul(zk[1], wk);
    #pragma unroll
    for (int k = 2; k < 12; ++k) { wk = cmul(wk, w1); zk[k] = cmul(zk[k], wk); }
    fft12<-1>(zk);
}

// ---- K1: forward row FFT (2 real rows packed), write transposed At[w][h] ----
__global__ __launch_bounds__(256, 3) void k_fft_rows_fwd(const float* __restrict__ x,
                                                         __half2* __restrict__ At) {
    __shared__ float2 lbuf[16 * LSTRB];
    int tid = threadIdx.x, grp = tid >> 5, l = tid & 31;
    int img = blockIdx.x / 12, g = blockIdx.x % 12;     // g: 32-row group
    const float* xi = x + (size_t)img * PLANE + (size_t)g * 32 * NFFT;
    #pragma unroll
    for (int pp = 0; pp < 2; ++pp) {
        int p = grp + 8 * pp;                           // local row-pair [0,16)
        const float* xa = xi + (size_t)(2 * p) * NFFT;
        const float* xb = xa + NFFT;
        float2 z[12];
        #pragma unroll
        for (int j = 0; j < 12; ++j) z[j] = make_float2(xa[32*j + l], xb[32*j + l]);
        fft384_reg<1>(z, l);
        int r = __brev((unsigned)l) >> 27;
        float2* s = lbuf + p * LSTRB;
        #pragma unroll
        for (int k = 0; k < 12; ++k) s[k + 12*r] = z[k];
    }
    __syncthreads();
    int h0 = g * 32;
    int q = l >> 1, odd = l & 1;
    #pragma unroll
    for (int pass = 0; pass < 13; ++pass) {
        #pragma unroll
        for (int ww = 0; ww < 2; ++ww) {
            int w = pass * 16 + grp * 2 + ww;
            if (w <= 192) {
                float2 Z  = lbuf[q * LSTRB + w];
                float2 Zm = lbuf[q * LSTRB + (w == 0 ? 0 : NFFT - w)];
                float2 v;
                if (odd) v = make_float2( 0.5f * (Z.y + Zm.y), -0.5f * (Z.x - Zm.x));  // Fb
                else     v = make_float2( 0.5f * (Z.x + Zm.x),  0.5f * (Z.y - Zm.y));  // Fa
                At[((size_t)img * NW + w) * NFFT + h0 + l] = __floats2half2_rn(v.x, v.y);
            }
        }
    }
}

// ---- K2: forward column FFT; coalesced loads (natural) and stores (P-layout) ----
__global__ __launch_bounds__(256, 8) void k_fft_cols_fwd(__half2* __restrict__ At) {
    int tid = threadIdx.x, grp = tid >> 5, l = tid & 31;
    int img = blockIdx.x / 25, cg = blockIdx.x % 25;
    int w = cg * 8 + grp;
    if (w > 192) return;                     // uniform per 32-lane group
    __half2* col = At + ((size_t)img * NW + w) * NFFT;
    float2 z[12];
    #pragma unroll
    for (int j = 0; j < 12; ++j) z[j] = __half22float2(col[32*j + l]);
    fft384_reg<1>(z, l);
    #pragma unroll
    for (int k = 0; k < 12; ++k)
        col[k * 32 + l] = __floats2half2_rn(z[k].x, z[k].y);   // P-layout, contiguous
}

// ---- K3: flag = sum(running_amp) via block partial + atomic ----
__global__ __launch_bounds__(256) void k_flag(const float* __restrict__ r,
                                              float* __restrict__ flag) {
    __shared__ float sm[256];
    int t = blockIdx.x * 1024 + threadIdx.x * 4;
    float4 v = *(const float4*)(r + t);
    sm[threadIdx.x] = v.x + v.y + v.z + v.w;
    __syncthreads();
    for (int s = 128; s > 0; s >>= 1) {
        if (threadIdx.x < s) sm[threadIdx.x] += sm[threadIdx.x + s];
        __syncthreads();
    }
    if (threadIdx.x == 0) atomicAdd(flag, sm[0]);
}

// ---- K4: batch-mean amplitude; elementwise over P-layout positions ----
__global__ __launch_bounds__(384) void k_amp(const __half2* __restrict__ At,
                                             float* __restrict__ ampm) {
    int c = blockIdx.x / NW;
    int w = blockIdx.x - c * NW;
    int h = threadIdx.x;
    const __half2* base = At + (size_t)w * NFFT + h;
    float s = 0.0f;
    #pragma unroll 4
    for (int b = 0; b < 32; ++b) {
        float2 z = __half22float2(base[(size_t)(b * 3 + c) * (NW * NFFT)]);
        s += sqrtf(z.x * z.x + z.y * z.y);
    }
    ampm[((size_t)c * NW + w) * NFFT + h] = s * (1.0f / 32.0f);
}

// ---- K5: rescale (P-layout elementwise) + DIT inverse col FFT -> natural order ----
__global__ __launch_bounds__(256, 8) void k_ifft_cols_scale(__half2* __restrict__ At,
                                                            const float* __restrict__ ampm,
                                                            const float* __restrict__ running,
                                                            const float* __restrict__ flag) {
    int tid = threadIdx.x, grp = tid >> 5, l = tid & 31;
    int img = blockIdx.x / 25, cg = blockIdx.x % 25;
    int w = cg * 8 + grp;
    if (w > 192) return;
    int c = img % 3;
    bool adopt = (flag[0] == 0.0f);
    int br = __brev((unsigned)l) >> 27;
    const float inv = 1.0f / (float)NFFT;
    __half2*     col = At + ((size_t)img * NW + w) * NFFT;
    const float* ac  = ampm + ((size_t)c * NW + w) * NFFT;
    float2 zk[12];
    #pragma unroll
    for (int k = 0; k < 12; ++k) {
        int pos = k * 32 + l;                         // P-layout, contiguous load
        float2 zv = __half22float2(col[pos]);
        float am = ac[pos];
        float na;
        if (adopt) na = am;
        else {
            int n = k + 12 * br;                      // natural spectral index
            na = 0.9f * running[((size_t)c * NFFT + n) * NFFT + w] + 0.1f * am;
        }
        float mag = sqrtf(zv.x*zv.x + zv.y*zv.y);
        if (mag > 0.0f) { float sc = na / mag; zk[k] = make_float2(zv.x*sc, zv.y*sc); }
        else            { zk[k] = make_float2(na, 0.0f); }
    }
    ifft384_dit(zk, l);
    #pragma unroll
    for (int j = 0; j < 12; ++j)
        col[32 * j + l] = __floats2half2_rn(zk[j].x * inv, zk[j].y * inv);  // natural, contiguous
}

// ---- K6: inverse row FFT (C2R) via LDS tile; DIT gather in, coalesced out ----
__global__ __launch_bounds__(256, 5) void k_ifft_rows_out(const __half2* __restrict__ At,
                                                          float* __restrict__ out) {
    __shared__ __half2 tile[NW * TSTR];
    int tid = threadIdx.x, grp = tid >> 5, l = tid & 31;
    int img = blockIdx.x / 12, g = blockIdx.x % 12;
    int h0 = g * 32;
    #pragma unroll
    for (int i = 0; i < 25; ++i) {
        int idx = i * 256 + tid;
        if (idx < NW * 32) {
            int w = idx >> 5, hh = idx & 31;
            tile[w * TSTR + hh] = At[((size_t)img * NW + w) * NFFT + h0 + hh];
        }
    }
    __syncthreads();
    const float inv = 1.0f / (float)NFFT;
    int br = __brev((unsigned)l) >> 27;
    #pragma unroll
    for (int pp = 0; pp < 2; ++pp) {
        int q = grp + 8 * pp;                       // local row-pair [0,16)
        float2 zk[12];
        #pragma unroll
        for (int k = 0; k < 12; ++k) {
            int n = k + 12 * br;                    // bit-reversed gather (LDS)
            if (n <= 192) {
                float2 Fa = __half22float2(tile[n * TSTR + 2*q]);
                float2 Fb = __half22float2(tile[n * TSTR + 2*q + 1]);
                zk[k] = make_float2(Fa.x - Fb.y, Fa.y + Fb.x);
            } else {
                int m2 = NFFT - n;
                float2 Fa = __half22float2(tile[m2 * TSTR + 2*q]);
                float2 Fb = __half22float2(tile[m2 * TSTR + 2*q + 1]);
                zk[k] = make_float2(Fa.x + Fb.y, Fb.x - Fa.y);
            }
        }
        ifft384_dit(zk, l);
        float* oa = out + (size_t)img * PLANE + (size_t)(h0 + 2*q) * NFFT;
        float* ob = oa + NFFT;
        #pragma unroll
        for (int j = 0; j < 12; ++j) {
            int n = 32 * j + l;                     // natural, contiguous stores
            oa[n] = zk[j].x * inv;
            ob[n] = zk[j].y * inv;
        }
    }
}

extern "C" void kernel_launch(void* const* d_in, const int* in_sizes, int n_in,
                              void* d_out, int out_size, void* d_ws, size_t ws_size,
                              hipStream_t stream) {
    const float* x       = (const float*)d_in[0];
    const float* running = (const float*)d_in[1];
    float* out = (float*)d_out;

    char* ws = (char*)d_ws;
    __half2* At   = (__half2*)ws;                       // 96*193*384*4 = 28,459,008 B
    float*   ampm = (float*)(ws + 28459008);            // 3*193*384*4 =     889,344 B
    float*   flag = (float*)(ws + 28459008 + 889344);   // 4 B

    hipMemsetAsync(flag, 0, 4, stream);
    k_flag<<<432, 256, 0, stream>>>(running, flag);
    k_fft_rows_fwd<<<IMGS * 12, 256, 0, stream>>>(x, At);
    k_fft_cols_fwd<<<IMGS * 25, 256, 0, stream>>>(At);
    k_amp<<<3 * NW, 384, 0, stream>>>(At, ampm);
    k_ifft_cols_scale<<<IMGS * 25, 256, 0, stream>>>(At, ampm, running, flag);
    k_ifft_rows_out<<<IMGS * 12, 256, 0, stream>>>(At, out);
}